// Round 8
// baseline (131.453 us; speedup 1.0000x reference)
//
#include <hip/hip_runtime.h>
#include <hip/hip_bf16.h>

#define N_  16384
#define D_  128
#define M1_ 64
#define K_  8
#define LOG2E 1.44269504088896f

typedef short short8 __attribute__((ext_vector_type(8)));
typedef float f32x4  __attribute__((ext_vector_type(4)));

__device__ __forceinline__ ushort f2bf(float f) {
    union { float f; unsigned u; } un; un.f = f;
    unsigned u = un.u;
    return (ushort)((u + 0x7fffu + ((u >> 16) & 1u)) >> 16);
}

// ---- fused prep, MFMA-fragment-order staging; W,b pre-scaled by log2(e) ----
// xbf: [n16][ks][lane][e], lane=(n&15)+16*((d>>3)&3) -> idx = n16*2048+ks*512+lane*8+(d&7)
// wbf: [j][ks*4+mt][lane][e], lane=(m&15)+16*((d>>3)&3)
// grid: [0,2048) x | [2048,3072) W | [3072,3104) vb
__global__ void prep_all(const float* __restrict__ x,
                         const float* __restrict__ w1p, const float* __restrict__ b1p,
                         const float* __restrict__ w1n, const float* __restrict__ b1n,
                         const float* __restrict__ w2,  const float* __restrict__ b2,
                         const float* __restrict__ w3,
                         ushort* __restrict__ xbf, ushort* __restrict__ wbf,
                         float* __restrict__ bp, float* __restrict__ vv,
                         float* __restrict__ cv) {
    int bx = blockIdx.x;
    if (bx < 2048) {                                   // x-cast+swizzle
        int i = bx * 256 + threadIdx.x;                // i < N_*D_/4
        int n = i >> 5;
        int d = (i & 31) * 4;                          // d%8 in {0,4}
        float4 f = ((const float4*)x)[i];
        ushort4 o;
        o.x = f2bf(f.x); o.y = f2bf(f.y); o.z = f2bf(f.z); o.w = f2bf(f.w);
        int lane = (n & 15) + 16 * ((d >> 3) & 3);
        int idx  = (n >> 4) * 2048 + (d >> 5) * 512 + lane * 8 + (d & 7);
        *(ushort4*)&xbf[idx] = o;
    } else if (bx < 3072) {                            // W mask+scale+cast+swizzle
        int i = (bx - 2048) * 256 + threadIdx.x;       // i < D_*M1_*D_/4
        int base = i * 4;
        int j   = base >> 13;
        int rem = base & 8191;
        int m   = rem >> 7;
        int d   = rem & 127;                           // d%8 in {0,4}
        float4 p = ((const float4*)w1p)[i];
        float4 n = ((const float4*)w1n)[i];
        float4 w;
        w.x = (p.x - n.x) * LOG2E; w.y = (p.y - n.y) * LOG2E;
        w.z = (p.z - n.z) * LOG2E; w.w = (p.w - n.w) * LOG2E;
        if (j == d    ) w.x = 0.f;
        if (j == d + 1) w.y = 0.f;
        if (j == d + 2) w.z = 0.f;
        if (j == d + 3) w.w = 0.f;
        ushort4 o;
        o.x = f2bf(w.x); o.y = f2bf(w.y); o.z = f2bf(w.z); o.w = f2bf(w.w);
        int lane = (m & 15) + 16 * ((d >> 3) & 3);
        int idx  = j * 8192 + ((d >> 5) * 4 + (m >> 4)) * 512 + lane * 8 + (d & 7);
        *(ushort4*)&wbf[idx] = o;
    } else {                                           // b/v/c fold (f32)
        int idx = (bx - 3072) * 256 + threadIdx.x;     // idx < D_*M1_
        int j = idx >> 6, m = idx & 63;
        float v = 0.f;
        for (int k = 0; k < K_; k++) v += w3[j * K_ + k] * w2[k * M1_ + m];
        vv[idx] = v;
        bp[idx] = (b1p[idx] - b1n[idx]) * LOG2E;       // log2e-scaled bias (C-init)
        if (m == 0) {
            float c = 0.f;
            for (int k = 0; k < K_; k++) c += w3[j * K_ + k] * b2[k];
            cv[j] = c;
        }
    }
}

// ---- main: grid (64 nblk, 128 j), 4 waves = {2 n-groups} x {2 m-halves}.
// Per wave: 2 m-tiles -> wfrag 32 regs, acc 8, half the epilogue chain.
// m-halves combine via 512B double-slot LDS + one barrier/st.
__global__ __launch_bounds__(256) void main_mfma(
    const ushort* __restrict__ xbf, const ushort* __restrict__ wbf,
    const float* __restrict__ bvec, const float* __restrict__ vvec,
    const float* __restrict__ cvec, float* __restrict__ out) {
    __shared__ float ldsbuf[2][64];                    // [st parity][wave*16+col]
    const int tid  = threadIdx.x;
    const int wave = tid >> 6, lane = tid & 63;
    const int quad = lane >> 4, col = lane & 15;
    const int mhalf = wave >> 1, ngrp = wave & 1;
    const int j    = blockIdx.y;
    const int nblk = blockIdx.x;                       // 0..63, fast dim -> XCD

    // W fragments (A operand), this wave's 2 m-tiles: mt = mhalf*2 + mtl
    short8 wfrag[2][4];                                // [mtl][ks]
    const ushort* wg = wbf + (size_t)j * 8192 + lane * 8;
    #pragma unroll
    for (int ks = 0; ks < 4; ks++)
        #pragma unroll
        for (int mtl = 0; mtl < 2; mtl++)
            wfrag[mtl][ks] = *(const short8*)&wg[(ks * 4 + mhalf * 2 + mtl) * 512];

    // epilogue constants (f32): lane's C-rows are m = (mhalf*2+mtl)*16 + quad*4 + r
    f32x4 bias4[2], vm4[2];
    #pragma unroll
    for (int mtl = 0; mtl < 2; mtl++) {
        bias4[mtl] = *(const f32x4*)&bvec[j * M1_ + (mhalf * 2 + mtl) * 16 + quad * 4];
        vm4[mtl]   = *(const f32x4*)&vvec[j * M1_ + (mhalf * 2 + mtl) * 16 + quad * 4];
    }
    const float cj = cvec[j];

    // x fragments (B operand): n16 = nblk*16 + st*2 + ngrp
    const ushort* xg = xbf + ((size_t)(nblk * 16 + ngrp)) * 2048 + lane * 8;
    float* outp = out + (size_t)(nblk * 256 + ngrp * 16 + col) * D_ + j;

    short8 abuf[2][4];
    #pragma unroll
    for (int ks = 0; ks < 4; ks++)
        abuf[0][ks] = *(const short8*)&xg[ks * 512];

    #pragma unroll
    for (int st = 0; st < 8; st++) {
        const int cur = st & 1, nxt = cur ^ 1;
        if (st < 7) {                                   // prefetch next subtile
            const ushort* xn = xg + (size_t)(st + 1) * 4096;
            #pragma unroll
            for (int ks = 0; ks < 4; ks++)
                abuf[nxt][ks] = *(const short8*)&xn[ks * 512];
        }

        f32x4 acc[2];
        #pragma unroll
        for (int mtl = 0; mtl < 2; mtl++) acc[mtl] = bias4[mtl];  // bias as C-init
        #pragma unroll
        for (int ks = 0; ks < 4; ks++)
            #pragma unroll
            for (int mtl = 0; mtl < 2; mtl++)
                acc[mtl] = __builtin_amdgcn_mfma_f32_16x16x32_bf16(
                               wfrag[mtl][ks], abuf[cur][ks], acc[mtl], 0, 0, 0);

        // s = 1/(1+2^-t); partial = sum over this lane's 8 m's of v[m]*s
        float partial = 0.f;
        #pragma unroll
        for (int mtl = 0; mtl < 2; mtl++)
            #pragma unroll
            for (int r = 0; r < 4; r++) {
                float e = __builtin_amdgcn_exp2f(-acc[mtl][r]);
                float s = __builtin_amdgcn_rcpf(1.0f + e);
                partial = fmaf(s, vm4[mtl][r], partial);
            }
        // sum across quads -> this wave's 32-m half-sum, in every lane
        partial += __shfl_xor(partial, 16);
        partial += __shfl_xor(partial, 32);

        // cross-wave combine of the two m-halves (wave w pairs with w+2)
        if (quad == 0) ldsbuf[cur][wave * 16 + col] = partial;
        __syncthreads();
        if (mhalf == 0 && quad == 0) {
            float other = ldsbuf[cur][(wave + 2) * 16 + col];
            outp[(size_t)st * 32 * D_] = partial + other + cj;
        }
    }
}

// ---- fp32 fallback (workspace too small) ----
__global__ void fallback_kernel(const float* __restrict__ x,
                                const float* __restrict__ w1p, const float* __restrict__ b1p,
                                const float* __restrict__ w1n, const float* __restrict__ b1n,
                                const float* __restrict__ w2,  const float* __restrict__ b2,
                                const float* __restrict__ w3,  float* __restrict__ out) {
    int n = blockIdx.x, j = blockIdx.y, m = threadIdx.x;
    const float* xr = x + (size_t)n * D_;
    const float* wp = w1p + ((size_t)j * M1_ + m) * D_;
    const float* wn = w1n + ((size_t)j * M1_ + m) * D_;
    float acc = 0.f;
    for (int d = 0; d < D_; d++) {
        if (d == j) continue;
        acc += xr[d] * (wp[d] - wn[d]);
    }
    acc += b1p[j * M1_ + m] - b1n[j * M1_ + m];
    float h = 1.f / (1.f + __expf(-acc));
    float vmv = 0.f;
    for (int k = 0; k < K_; k++) vmv += w3[j * K_ + k] * w2[k * M1_ + m];
    float p = h * vmv;
    for (int off = 1; off < 64; off <<= 1) p += __shfl_xor(p, off);
    if (m == 0) {
        float c = 0.f;
        for (int k = 0; k < K_; k++) c += w3[j * K_ + k] * b2[k];
        out[(size_t)n * D_ + j] = p + c;
    }
}

extern "C" void kernel_launch(void* const* d_in, const int* in_sizes, int n_in,
                              void* d_out, int out_size, void* d_ws, size_t ws_size,
                              hipStream_t stream) {
    const float* x   = (const float*)d_in[0];
    const float* w1p = (const float*)d_in[1];
    const float* b1p = (const float*)d_in[2];
    const float* w1n = (const float*)d_in[3];
    const float* b1n = (const float*)d_in[4];
    const float* w2  = (const float*)d_in[5];
    const float* b2  = (const float*)d_in[6];
    const float* w3  = (const float*)d_in[7];
    float* out = (float*)d_out;

    const size_t off_x = 0;
    const size_t off_w = off_x + (size_t)N_ * D_ * 2;          // x bf16: 4 MB
    const size_t off_b = off_w + (size_t)D_ * M1_ * D_ * 2;    // W bf16: 2 MB
    const size_t off_v = off_b + (size_t)D_ * M1_ * 4;
    const size_t off_c = off_v + (size_t)D_ * M1_ * 4;
    const size_t need  = off_c + (size_t)D_ * 4;

    if (ws_size < need) {
        fallback_kernel<<<dim3(N_, D_), 64, 0, stream>>>(x, w1p, b1p, w1n, b1n, w2, b2, w3, out);
        return;
    }

    ushort* xbf = (ushort*)((char*)d_ws + off_x);
    ushort* wbf = (ushort*)((char*)d_ws + off_w);
    float*  bp  = (float*)((char*)d_ws + off_b);
    float*  vv  = (float*)((char*)d_ws + off_v);
    float*  cv  = (float*)((char*)d_ws + off_c);

    prep_all<<<3104, 256, 0, stream>>>(x, w1p, b1p, w1n, b1n, w2, b2, w3,
                                       xbf, wbf, bp, vv, cv);
    main_mfma<<<dim3(64, 128), 256, 0, stream>>>(xbf, wbf, bp, vv, cv, out);
}

// Round 9
// 121.488 us; speedup vs baseline: 1.0820x; 1.0820x over previous
//
#include <hip/hip_runtime.h>
#include <hip/hip_bf16.h>

#define N_  16384
#define D_  128
#define M1_ 64
#define K_  8
#define LOG2E 1.44269504088896f

typedef short short8 __attribute__((ext_vector_type(8)));
typedef float f32x4  __attribute__((ext_vector_type(4)));

__device__ __forceinline__ ushort f2bf(float f) {
    union { float f; unsigned u; } un; un.f = f;
    unsigned u = un.u;
    return (ushort)((u + 0x7fffu + ((u >> 16) & 1u)) >> 16);
}

// ---- fused prep, MFMA-fragment-order staging; W,b pre-scaled by log2(e) ----
// xbf: [n16][ks][lane][e], lane=(n&15)+16*((d>>3)&3) -> idx = n16*2048+ks*512+lane*8+(d&7)
// wbf: [j][ks*4+mt][lane][e], lane=(m&15)+16*((d>>3)&3)
// grid: [0,2048) x | [2048,3072) W | [3072,3104) vb
__global__ void prep_all(const float* __restrict__ x,
                         const float* __restrict__ w1p, const float* __restrict__ b1p,
                         const float* __restrict__ w1n, const float* __restrict__ b1n,
                         const float* __restrict__ w2,  const float* __restrict__ b2,
                         const float* __restrict__ w3,
                         ushort* __restrict__ xbf, ushort* __restrict__ wbf,
                         float* __restrict__ bp, float* __restrict__ vv,
                         float* __restrict__ cv) {
    int bx = blockIdx.x;
    if (bx < 2048) {                                   // x-cast+swizzle
        int i = bx * 256 + threadIdx.x;                // i < N_*D_/4
        int n = i >> 5;
        int d = (i & 31) * 4;                          // d%8 in {0,4}
        float4 f = ((const float4*)x)[i];
        ushort4 o;
        o.x = f2bf(f.x); o.y = f2bf(f.y); o.z = f2bf(f.z); o.w = f2bf(f.w);
        int lane = (n & 15) + 16 * ((d >> 3) & 3);
        int idx  = (n >> 4) * 2048 + (d >> 5) * 512 + lane * 8 + (d & 7);
        *(ushort4*)&xbf[idx] = o;
    } else if (bx < 3072) {                            // W mask+scale+cast+swizzle
        int i = (bx - 2048) * 256 + threadIdx.x;       // i < D_*M1_*D_/4
        int base = i * 4;
        int j   = base >> 13;
        int rem = base & 8191;
        int m   = rem >> 7;
        int d   = rem & 127;                           // d%8 in {0,4}
        float4 p = ((const float4*)w1p)[i];
        float4 n = ((const float4*)w1n)[i];
        float4 w;
        w.x = (p.x - n.x) * LOG2E; w.y = (p.y - n.y) * LOG2E;
        w.z = (p.z - n.z) * LOG2E; w.w = (p.w - n.w) * LOG2E;
        if (j == d    ) w.x = 0.f;
        if (j == d + 1) w.y = 0.f;
        if (j == d + 2) w.z = 0.f;
        if (j == d + 3) w.w = 0.f;
        ushort4 o;
        o.x = f2bf(w.x); o.y = f2bf(w.y); o.z = f2bf(w.z); o.w = f2bf(w.w);
        int lane = (m & 15) + 16 * ((d >> 3) & 3);
        int idx  = j * 8192 + ((d >> 5) * 4 + (m >> 4)) * 512 + lane * 8 + (d & 7);
        *(ushort4*)&wbf[idx] = o;
    } else {                                           // b/v/c fold (f32)
        int idx = (bx - 3072) * 256 + threadIdx.x;     // idx < D_*M1_
        int j = idx >> 6, m = idx & 63;
        float v = 0.f;
        for (int k = 0; k < K_; k++) v += w3[j * K_ + k] * w2[k * M1_ + m];
        vv[idx] = v;
        bp[idx] = (b1p[idx] - b1n[idx]) * LOG2E;       // log2e-scaled bias (C-init)
        if (m == 0) {
            float c = 0.f;
            for (int k = 0; k < K_; k++) c += w3[j * K_ + k] * b2[k];
            cv[j] = c;
        }
    }
}

// ---- main: grid (32 nblk, 128 j). Hot loop = MFMA + sigmoid + fma ONLY —
// all DS shuffles and stores hoisted to a single tail phase (pr[8] regs).
__global__ __launch_bounds__(256) void main_mfma(
    const ushort* __restrict__ xbf, const ushort* __restrict__ wbf,
    const float* __restrict__ bvec, const float* __restrict__ vvec,
    const float* __restrict__ cvec, float* __restrict__ out) {
    const int tid  = threadIdx.x;
    const int wave = tid >> 6, lane = tid & 63;
    const int quad = lane >> 4, col = lane & 15;
    const int j    = blockIdx.y;
    const int nblk = blockIdx.x;                       // fast dim -> XCD = nblk%8

    // W fragments (A operand): one coalesced 16B/lane load each
    short8 wfrag[4][4];                                // [mt][ks]
    const ushort* wg = wbf + (size_t)j * 8192 + lane * 8;
    #pragma unroll
    for (int ks = 0; ks < 4; ks++)
        #pragma unroll
        for (int mt = 0; mt < 4; mt++)
            wfrag[mt][ks] = *(const short8*)&wg[(ks * 4 + mt) * 512];

    // epilogue constants (f32): lane's C-rows are m = mt*16 + quad*4 + r
    f32x4 bias4[4], vm4[4];
    #pragma unroll
    for (int mt = 0; mt < 4; mt++) {
        bias4[mt] = *(const f32x4*)&bvec[j * M1_ + mt * 16 + quad * 4];
        vm4[mt]   = *(const f32x4*)&vvec[j * M1_ + mt * 16 + quad * 4];
    }
    const float cj = cvec[j];

    // x fragments (B operand): n16 = nblk*32 + wave + st*4
    const ushort* xg = xbf + ((size_t)(nblk * 32 + wave)) * 2048 + lane * 8;
    float* outp = out + (size_t)(nblk * 512 + wave * 16 + col) * D_ + j;

    short8 abuf[2][4];
    #pragma unroll
    for (int ks = 0; ks < 4; ks++)
        abuf[0][ks] = *(const short8*)&xg[ks * 512];

    float pr[8];                                       // per-st partial sums

    #pragma unroll
    for (int st = 0; st < 8; st++) {
        const int cur = st & 1, nxt = cur ^ 1;
        if (st < 7) {                                   // prefetch next subtile
            const ushort* xn = xg + (size_t)(st + 1) * 8192;
            #pragma unroll
            for (int ks = 0; ks < 4; ks++)
                abuf[nxt][ks] = *(const short8*)&xn[ks * 512];
        }

        f32x4 acc[4];
        #pragma unroll
        for (int mt = 0; mt < 4; mt++) acc[mt] = bias4[mt];   // bias as C-init
        #pragma unroll
        for (int ks = 0; ks < 4; ks++)
            #pragma unroll
            for (int mt = 0; mt < 4; mt++)
                acc[mt] = __builtin_amdgcn_mfma_f32_16x16x32_bf16(
                              wfrag[mt][ks], abuf[cur][ks], acc[mt], 0, 0, 0);

        // s = 1/(1+2^-t); pr[st] = sum over this lane's 16 m's of v[m]*s
        float partial = 0.f;
        #pragma unroll
        for (int mt = 0; mt < 4; mt++)
            #pragma unroll
            for (int r = 0; r < 4; r++) {
                float e = __builtin_amdgcn_exp2f(-acc[mt][r]);
                float s = __builtin_amdgcn_rcpf(1.0f + e);
                partial = fmaf(s, vm4[mt][r], partial);
            }
        pr[st] = partial;                               // NO shuffles/stores in loop
    }

    // tail: 16 independent cross-quad shuffles (pipelined), then 8 stores
    #pragma unroll
    for (int st = 0; st < 8; st++)
        pr[st] += __shfl_xor(pr[st], 16);
    #pragma unroll
    for (int st = 0; st < 8; st++)
        pr[st] += __shfl_xor(pr[st], 32);
    if (quad == 0) {
        #pragma unroll
        for (int st = 0; st < 8; st++)
            outp[(size_t)st * 64 * D_] = pr[st] + cj;
    }
}

// ---- fp32 fallback (workspace too small) ----
__global__ void fallback_kernel(const float* __restrict__ x,
                                const float* __restrict__ w1p, const float* __restrict__ b1p,
                                const float* __restrict__ w1n, const float* __restrict__ b1n,
                                const float* __restrict__ w2,  const float* __restrict__ b2,
                                const float* __restrict__ w3,  float* __restrict__ out) {
    int n = blockIdx.x, j = blockIdx.y, m = threadIdx.x;
    const float* xr = x + (size_t)n * D_;
    const float* wp = w1p + ((size_t)j * M1_ + m) * D_;
    const float* wn = w1n + ((size_t)j * M1_ + m) * D_;
    float acc = 0.f;
    for (int d = 0; d < D_; d++) {
        if (d == j) continue;
        acc += xr[d] * (wp[d] - wn[d]);
    }
    acc += b1p[j * M1_ + m] - b1n[j * M1_ + m];
    float h = 1.f / (1.f + __expf(-acc));
    float vmv = 0.f;
    for (int k = 0; k < K_; k++) vmv += w3[j * K_ + k] * w2[k * M1_ + m];
    float p = h * vmv;
    for (int off = 1; off < 64; off <<= 1) p += __shfl_xor(p, off);
    if (m == 0) {
        float c = 0.f;
        for (int k = 0; k < K_; k++) c += w3[j * K_ + k] * b2[k];
        out[(size_t)n * D_ + j] = p + c;
    }
}

extern "C" void kernel_launch(void* const* d_in, const int* in_sizes, int n_in,
                              void* d_out, int out_size, void* d_ws, size_t ws_size,
                              hipStream_t stream) {
    const float* x   = (const float*)d_in[0];
    const float* w1p = (const float*)d_in[1];
    const float* b1p = (const float*)d_in[2];
    const float* w1n = (const float*)d_in[3];
    const float* b1n = (const float*)d_in[4];
    const float* w2  = (const float*)d_in[5];
    const float* b2  = (const float*)d_in[6];
    const float* w3  = (const float*)d_in[7];
    float* out = (float*)d_out;

    const size_t off_x = 0;
    const size_t off_w = off_x + (size_t)N_ * D_ * 2;          // x bf16: 4 MB
    const size_t off_b = off_w + (size_t)D_ * M1_ * D_ * 2;    // W bf16: 2 MB
    const size_t off_v = off_b + (size_t)D_ * M1_ * 4;
    const size_t off_c = off_v + (size_t)D_ * M1_ * 4;
    const size_t need  = off_c + (size_t)D_ * 4;

    if (ws_size < need) {
        fallback_kernel<<<dim3(N_, D_), 64, 0, stream>>>(x, w1p, b1p, w1n, b1n, w2, b2, w3, out);
        return;
    }

    ushort* xbf = (ushort*)((char*)d_ws + off_x);
    ushort* wbf = (ushort*)((char*)d_ws + off_w);
    float*  bp  = (float*)((char*)d_ws + off_b);
    float*  vv  = (float*)((char*)d_ws + off_v);
    float*  cv  = (float*)((char*)d_ws + off_c);

    prep_all<<<3104, 256, 0, stream>>>(x, w1p, b1p, w1n, b1n, w2, b2, w3,
                                       xbf, wbf, bp, vv, cv);
    main_mfma<<<dim3(32, 128), 256, 0, stream>>>(xbf, wbf, bp, vv, cv, out);
}